// Round 5
// baseline (1203.866 us; speedup 1.0000x reference)
//
#include <hip/hip_runtime.h>
#include <hip/hip_bf16.h>
#include <stdint.h>

#define NE 131072

typedef __attribute__((ext_vector_type(8))) short bf16x8;
typedef __attribute__((ext_vector_type(4))) float f32x4;

__device__ __forceinline__ unsigned short f2bf(float f) {
  unsigned u = __float_as_uint(f);
  u += 0x7FFF + ((u >> 16) & 1);   // round-to-nearest-even
  return (unsigned short)(u >> 16);
}
__device__ __forceinline__ float bf2f(unsigned short h) {
  return __uint_as_float((unsigned)h << 16);
}

__device__ __forceinline__ void gload_lds16(const void* g, void* l) {
  __builtin_amdgcn_global_load_lds(
      (const __attribute__((address_space(1))) unsigned*)g,
      (__attribute__((address_space(3))) unsigned*)l, 16, 0, 0);
}

// Fused weight prep: 12 (job,z) units on blockIdx.y, LDS-tiled transpose+cvt.
__global__ void weight_prep(const float* __restrict__ W0, const float* __restrict__ W1,
                            const float* __restrict__ W2, const float* __restrict__ SW0,
                            const float* __restrict__ SW1, const float* __restrict__ SW2,
                            unsigned short* W0t, unsigned short* W1t,
                            unsigned short* W2t, unsigned short* SW0t,
                            unsigned short* SW1t, unsigned short* SW2b) {
  __shared__ float tile[32][33];
  const int u = blockIdx.y;
  const float* src; unsigned short* dst; int K, Nc;
  if (u == 0)      { src = W0;  dst = W0t;  K = 64;  Nc = 512; }
  else if (u == 1) { src = W1;  dst = W1t;  K = 512; Nc = 512; }
  else if (u == 2) { src = W2;  dst = W2t;  K = 512; Nc = 512; }
  else if (u < 6)  { int p = u - 3; src = SW0 + (long)p * 512 * 512; dst = SW0t + (long)p * 512 * 512; K = 512; Nc = 512; }
  else if (u < 9)  { int p = u - 6; src = SW1 + (long)p * 512 * 256; dst = SW1t + (long)p * 256 * 512; K = 512; Nc = 256; }
  else             { int p = u - 9; src = SW2 + (long)p * 256;       dst = SW2b + (long)p * 256;       K = 256; Nc = 1; }
  const int tkn = K >> 5;
  const int tk = blockIdx.x % tkn, tn = blockIdx.x / tkn;
  if (tn >= ((Nc + 31) >> 5)) return;
  const int k0 = tk * 32, n0 = tn * 32;
  const int tx = threadIdx.x & 31, ty = threadIdx.x >> 5;
  if (n0 + tx < Nc)
#pragma unroll
    for (int j = 0; j < 4; ++j)
      tile[ty * 4 + j][tx] = src[(long)(k0 + ty * 4 + j) * Nc + n0 + tx];
  __syncthreads();
#pragma unroll
  for (int j = 0; j < 4; ++j) {
    int n = n0 + ty * 4 + j;
    if (n < Nc) dst[(long)n * K + k0 + tx] = f2bf(tile[tx][ty * 4 + j]);
  }
}

__global__ void relu_cvt_x(const float4* __restrict__ x,
                           ushort4* __restrict__ xb) {
  int i = blockIdx.x * blockDim.x + threadIdx.x;
  float4 v = x[i];
  ushort4 o;
  o.x = f2bf(fmaxf(v.x, 0.f));
  o.y = f2bf(fmaxf(v.y, 0.f));
  o.z = f2bf(fmaxf(v.z, 0.f));
  o.w = f2bf(fmaxf(v.w, 0.f));
  xb[i] = o;
}

// C[128rows x 512] = A[rows x K] * Bt[512 x K]^T + bias. Full-width BN=512.
// K-MAJOR LDS staging [kc][rows][8]: conflict-free ds_read_b128 fragments.
__global__ __launch_bounds__(512) void gemmW(
    const unsigned short* __restrict__ A,
    const unsigned short* __restrict__ Bt,
    const float* __restrict__ bias,
    float* __restrict__ outF,
    unsigned short* __restrict__ outA,
    int K) {
  __shared__ unsigned short As[4 * 128 * 8];   // 8 KB  [kc][128][8]
  __shared__ unsigned short Bs[4 * 512 * 8];   // 32 KB [kc][512][8]
  const int tid = threadIdx.x;
  const int wave = tid >> 6, lane = tid & 63;
  const int wm = wave >> 2, wn = wave & 3;
  const int lr = lane & 15, lh = lane >> 4;
  const long row0 = (long)blockIdx.x * 128;

  f32x4 acc[4][8];
#pragma unroll
  for (int m = 0; m < 4; ++m)
#pragma unroll
    for (int n = 0; n < 8; ++n) acc[m][n] = (f32x4){0.f, 0.f, 0.f, 0.f};

  const int nk = K >> 5;
  const int akc = wave >> 1, arb = (wave & 1) * 64;   // A-stage kc, row base
  for (int kt = 0; kt < nk; ++kt) {
    const int k0 = kt << 5;
    // A: 512 chunks, 1/thread. chunk c = wave*64+lane -> kc=c>>7, row=c&127
    gload_lds16(A + (row0 + arb + lane) * K + k0 + akc * 8,
                &As[wave * 64 * 8]);
    // B: 2048 chunks, 4/thread. c = i*512 + tid -> kc=i, row=tid
#pragma unroll
    for (int i = 0; i < 4; ++i)
      gload_lds16(Bt + (long)tid * K + k0 + i * 8,
                  &Bs[(i * 512 + wave * 64) * 8]);
    __syncthreads();
    bf16x8 a[4], b[8];
#pragma unroll
    for (int m = 0; m < 4; ++m)
      a[m] = *(const bf16x8*)&As[lh * 1024 + (wm * 64 + m * 16 + lr) * 8];
#pragma unroll
    for (int n = 0; n < 8; ++n)
      b[n] = *(const bf16x8*)&Bs[lh * 4096 + (wn * 128 + n * 16 + lr) * 8];
#pragma unroll
    for (int m = 0; m < 4; ++m)
#pragma unroll
      for (int n = 0; n < 8; ++n)
        acc[m][n] =
            __builtin_amdgcn_mfma_f32_16x16x32_bf16(a[m], b[n], acc[m][n], 0, 0, 0);
    __syncthreads();
  }

  float bv[8];
#pragma unroll
  for (int n = 0; n < 8; ++n) bv[n] = bias[wn * 128 + n * 16 + lr];
#pragma unroll
  for (int m = 0; m < 4; ++m) {
#pragma unroll
    for (int r = 0; r < 4; ++r) {
      long e = row0 + wm * 64 + m * 16 + lh * 4 + r;
#pragma unroll
      for (int n = 0; n < 8; ++n) {
        int oc = wn * 128 + n * 16 + lr;
        float v = acc[m][n][r] + bv[n];
        if (outF) outF[e * 512 + oc] = v;
        if (outA) outA[e * 512 + oc] = f2bf(fmaxf(v, 0.f));
      }
    }
  }
}

// Fused subnet kernel, 64 events/block, 2 blocks/CU.
// Phase 1 (swapped SW0): h0^T[512h x 64e]; waves = 8 h-groups, each does all e.
//   K-major staging (conflict-free); staging aliases h0.
// Pack relu(h0+b) -> h0[e][512] bf16, XOR-swizzled (2-way max).
// Phase 2 (SW1): waves = 8 oc-groups of 32; A from swizzled h0, B from L2.
// Epilogue: fused 256->1 head + sigmoid/clip/ratio/mask.
__global__ __launch_bounds__(512, 4) void subnet_fused(
    const unsigned short* __restrict__ bufR,   // [rows][512] bf16 relu(repr)
    const unsigned short* __restrict__ SW0t,   // [P][512h][512d]
    const float* __restrict__ Sb0,             // [P][512]
    const unsigned short* __restrict__ SW1t,   // [P][256][512]
    const float* __restrict__ Sb1,             // [P][256]
    const unsigned short* __restrict__ W2b,    // [P][256]
    const float* __restrict__ Sb2,             // [P]
    const int* __restrict__ y, const int* __restrict__ pairs,
    int r0,
    float* __restrict__ outR, float* __restrict__ outS,
    float* __restrict__ outM) {
  __shared__ unsigned short h0[32768];   // 64 KB; staging aliases first 36 KB
  __shared__ float lbias[512];
  __shared__ float part[8][64];
  const int p = blockIdx.z;
  const int tid = threadIdx.x, wv = tid >> 6, lane = tid & 63;
  const int lr = lane & 15, lh = lane >> 4;
  const long erow0 = (long)blockIdx.x * 64;
  const unsigned short* Wt = SW0t + (long)p * 512 * 512;
  const unsigned short* Rb = bufR + erow0 * 512;

  lbias[tid] = Sb0[p * 512 + tid];

  // ---- phase 1: Ast = h0[0..16384) as [kc4][512][8]; Bst = h0+16384 [kc4][64][8]
  f32x4 acc[4][4];
#pragma unroll
  for (int m = 0; m < 4; ++m)
#pragma unroll
    for (int n = 0; n < 4; ++n) acc[m][n] = (f32x4){0.f, 0.f, 0.f, 0.f};

  for (int kt = 0; kt < 16; ++kt) {
    const int k0 = kt << 5;
    // A: 2048 chunks, 4/thread: c = wv*256 + i*64 + lane -> kc=c>>9, row=c&511
#pragma unroll
    for (int i = 0; i < 4; ++i) {
      const int cb = wv * 256 + i * 64;
      const int kc = cb >> 9, rowb = cb & 511;
      gload_lds16(Wt + (long)(rowb + lane) * 512 + k0 + kc * 8, &h0[cb * 8]);
    }
    // B: 256 chunks, waves 0-3: c = wv*64+lane -> kc=wv, row=lane
    if (wv < 4)
      gload_lds16(Rb + (long)lane * 512 + k0 + wv * 8, &h0[16384 + wv * 512]);
    __syncthreads();
    bf16x8 a[4], b[4];
#pragma unroll
    for (int m = 0; m < 4; ++m)
      a[m] = *(const bf16x8*)&h0[lh * 4096 + (wv * 64 + m * 16 + lr) * 8];
#pragma unroll
    for (int n = 0; n < 4; ++n)
      b[n] = *(const bf16x8*)&h0[16384 + lh * 512 + (n * 16 + lr) * 8];
#pragma unroll
    for (int m = 0; m < 4; ++m)
#pragma unroll
      for (int n = 0; n < 4; ++n)
        acc[m][n] =
            __builtin_amdgcn_mfma_f32_16x16x32_bf16(a[m], b[n], acc[m][n], 0, 0, 0);
    __syncthreads();
  }

  // pack relu(acc+bias) -> h0[e][h] bf16, byte = (e*1024 + h*2) ^ ((e&7)<<4)
#pragma unroll
  for (int m = 0; m < 4; ++m) {
    const int h4 = wv * 64 + m * 16 + lh * 4;
    const f32x4 bv = *(const f32x4*)&lbias[h4];
#pragma unroll
    for (int n = 0; n < 4; ++n) {
      const int e = n * 16 + lr;
      uint2 v;
      unsigned short p0 = f2bf(fmaxf(acc[m][n][0] + bv[0], 0.f));
      unsigned short p1 = f2bf(fmaxf(acc[m][n][1] + bv[1], 0.f));
      unsigned short p2 = f2bf(fmaxf(acc[m][n][2] + bv[2], 0.f));
      unsigned short p3 = f2bf(fmaxf(acc[m][n][3] + bv[3], 0.f));
      v.x = (unsigned)p0 | ((unsigned)p1 << 16);
      v.y = (unsigned)p2 | ((unsigned)p3 << 16);
      const int byte = (e * 1024 + h4 * 2) ^ ((e & 7) << 4);
      *reinterpret_cast<uint2*>(reinterpret_cast<char*>(h0) + byte) = v;
    }
  }
  __syncthreads();

  // ---- phase 2: wave wv owns outcols [wv*32, wv*32+32); no barriers
  const unsigned short* W1p = SW1t + (long)p * 256 * 512;
  f32x4 acc2[4][2];
#pragma unroll
  for (int m = 0; m < 4; ++m)
#pragma unroll
    for (int n = 0; n < 2; ++n) acc2[m][n] = (f32x4){0.f, 0.f, 0.f, 0.f};

  for (int kt = 0; kt < 16; ++kt) {
    const int k = kt * 32 + lh * 8;
    bf16x8 a2[4], b2[2];
#pragma unroll
    for (int m = 0; m < 4; ++m) {
      const int e = m * 16 + lr;
      const int byte = (e * 1024 + k * 2) ^ ((e & 7) << 4);
      a2[m] = *reinterpret_cast<const bf16x8*>(
          reinterpret_cast<const char*>(h0) + byte);
    }
#pragma unroll
    for (int n = 0; n < 2; ++n) {
      const int oc = wv * 32 + n * 16 + lr;
      b2[n] = *(const bf16x8*)&W1p[(long)oc * 512 + k];
    }
#pragma unroll
    for (int m = 0; m < 4; ++m)
#pragma unroll
      for (int n = 0; n < 2; ++n)
        acc2[m][n] =
            __builtin_amdgcn_mfma_f32_16x16x32_bf16(a2[m], b2[n], acc2[m][n], 0, 0, 0);
  }

  // ---- fused head ----
  float b1v[2], w2v[2];
#pragma unroll
  for (int n = 0; n < 2; ++n) {
    const int oc = wv * 32 + n * 16 + lr;
    b1v[n] = Sb1[p * 256 + oc];
    w2v[n] = bf2f(W2b[p * 256 + oc]);
  }
#pragma unroll
  for (int m = 0; m < 4; ++m) {
#pragma unroll
    for (int r = 0; r < 4; ++r) {
      float s = 0.f;
#pragma unroll
      for (int n = 0; n < 2; ++n)
        s += fmaxf(acc2[m][n][r] + b1v[n], 0.f) * w2v[n];
#pragma unroll
      for (int off = 1; off < 16; off <<= 1) s += __shfl_xor(s, off);
      if (lr == 0) part[wv][m * 16 + lh * 4 + r] = s;
    }
  }
  __syncthreads();
  if (tid < 64) {
    float logit = Sb2[p];
#pragma unroll
    for (int w = 0; w < 8; ++w) logit += part[w][tid];
    float s = 1.f / (1.f + expf(-logit));
    s = fmaxf(s, 1e-9f);
    float rr = (1.f - s) / s;
    long n = r0 + erow0 + tid;
    int yv = y[n];
    float mf = (yv == pairs[p * 2] || yv == pairs[p * 2 + 1]) ? 1.f : 0.f;
    outR[(long)p * NE + n] = rr * mf;
    outS[(long)p * NE + n] = s * mf;
    outM[(long)p * NE + n] = mf;
  }
}

extern "C" void kernel_launch(void* const* d_in, const int* in_sizes, int n_in,
                              void* d_out, int out_size, void* d_ws, size_t ws_size,
                              hipStream_t stream) {
  const float* x   = (const float*)d_in[0];
  const int*   y   = (const int*)d_in[1];
  const int*   prs = (const int*)d_in[2];
  const float* W0  = (const float*)d_in[3];
  const float* b0  = (const float*)d_in[4];
  const float* W1  = (const float*)d_in[5];
  const float* b1  = (const float*)d_in[6];
  const float* W2  = (const float*)d_in[7];
  const float* b2  = (const float*)d_in[8];
  const float* SW0 = (const float*)d_in[9];
  const float* Sb0 = (const float*)d_in[10];
  const float* SW1 = (const float*)d_in[11];
  const float* Sb1 = (const float*)d_in[12];
  const float* SW2 = (const float*)d_in[13];
  const float* Sb2 = (const float*)d_in[14];

  uint8_t* ws = (uint8_t*)d_ws;
  size_t off = 0;
  auto take = [&](size_t bytes) -> void* {
    void* ptr = ws + off;
    off = (off + bytes + 255) & ~(size_t)255;
    return ptr;
  };
  unsigned short* W0t  = (unsigned short*)take((size_t)64 * 512 * 2);
  unsigned short* W1t  = (unsigned short*)take((size_t)512 * 512 * 2);
  unsigned short* W2t  = (unsigned short*)take((size_t)512 * 512 * 2);
  unsigned short* SW0t = (unsigned short*)take((size_t)3 * 512 * 512 * 2);
  unsigned short* SW1t = (unsigned short*)take((size_t)3 * 256 * 512 * 2);
  unsigned short* SW2b = (unsigned short*)take((size_t)3 * 256 * 2);
  unsigned short* Xb   = (unsigned short*)take((size_t)NE * 64 * 2);
  size_t fixed = off;

  int chunk = 32768;
  if (ws_size >= fixed + (size_t)2 * 131072 * 1024 + 4096) chunk = 131072;
  else if (ws_size >= fixed + (size_t)2 * 65536 * 1024 + 4096) chunk = 65536;

  unsigned short* T0 = (unsigned short*)take((size_t)chunk * 512 * 2);
  unsigned short* T1 = (unsigned short*)take((size_t)chunk * 512 * 2);
  unsigned short* bufR = T0;  // alias: T0 dead once L2 runs (L2 reads T1)

  float* out   = (float*)d_out;
  float* outRe = out;
  float* outR  = out + (size_t)NE * 512;
  float* outS  = outR + (size_t)3 * NE;
  float* outM  = outS + (size_t)3 * NE;

  weight_prep<<<dim3(256, 12), 256, 0, stream>>>(W0, W1, W2, SW0, SW1, SW2,
                                                 W0t, W1t, W2t, SW0t, SW1t, SW2b);
  relu_cvt_x<<<dim3(NE * 64 / 4 / 256), 256, 0, stream>>>((const float4*)x,
                                                          (ushort4*)Xb);

  for (int r0 = 0; r0 < NE; r0 += chunk) {
    gemmW<<<dim3(chunk / 128), 512, 0, stream>>>(
        Xb + (size_t)r0 * 64, W0t, b0, nullptr, T0, 64);
    gemmW<<<dim3(chunk / 128), 512, 0, stream>>>(T0, W1t, b1, nullptr, T1, 512);
    gemmW<<<dim3(chunk / 128), 512, 0, stream>>>(
        T1, W2t, b2, outRe + (size_t)r0 * 512, bufR, 512);
    subnet_fused<<<dim3(chunk / 64, 1, 3), 512, 0, stream>>>(
        bufR, SW0t, Sb0, SW1t, Sb1, SW2b, Sb2, y, prs, r0, outR, outS, outM);
  }
}

// Round 6
// 882.225 us; speedup vs baseline: 1.3646x; 1.3646x over previous
//
#include <hip/hip_runtime.h>
#include <stdint.h>

#define NE 131072

typedef __attribute__((ext_vector_type(8))) short bf16x8;
typedef __attribute__((ext_vector_type(4))) float f32x4;

static __device__ __forceinline__ unsigned short f2bf(float f) {
  unsigned u = __float_as_uint(f);
  u += 0x7FFF + ((u >> 16) & 1);   // round-to-nearest-even
  return (unsigned short)(u >> 16);
}
static __device__ __forceinline__ float bf2f(unsigned short h) {
  return __uint_as_float((unsigned)h << 16);
}
static __device__ __forceinline__ void gload_lds16(const void* g, void* l) {
  __builtin_amdgcn_global_load_lds(
      (const __attribute__((address_space(1))) unsigned*)g,
      (__attribute__((address_space(3))) unsigned*)l, 16, 0, 0);
}

// Fused weight prep (verified R4/R5): dst[n][k] = bf16(src[k][n])
__global__ void weight_prep(const float* __restrict__ W0, const float* __restrict__ W1,
                            const float* __restrict__ W2, const float* __restrict__ SW0,
                            const float* __restrict__ SW1, const float* __restrict__ SW2,
                            unsigned short* W0t, unsigned short* W1t,
                            unsigned short* W2t, unsigned short* SW0t,
                            unsigned short* SW1t, unsigned short* SW2b) {
  __shared__ float tile[32][33];
  const int u = blockIdx.y;
  const float* src; unsigned short* dst; int K, Nc;
  if (u == 0)      { src = W0;  dst = W0t;  K = 64;  Nc = 512; }
  else if (u == 1) { src = W1;  dst = W1t;  K = 512; Nc = 512; }
  else if (u == 2) { src = W2;  dst = W2t;  K = 512; Nc = 512; }
  else if (u < 6)  { int p = u - 3; src = SW0 + (long)p * 512 * 512; dst = SW0t + (long)p * 512 * 512; K = 512; Nc = 512; }
  else if (u < 9)  { int p = u - 6; src = SW1 + (long)p * 512 * 256; dst = SW1t + (long)p * 256 * 512; K = 512; Nc = 256; }
  else             { int p = u - 9; src = SW2 + (long)p * 256;       dst = SW2b + (long)p * 256;       K = 256; Nc = 1; }
  const int tkn = K >> 5;
  const int tk = blockIdx.x % tkn, tn = blockIdx.x / tkn;
  if (tn >= ((Nc + 31) >> 5)) return;
  const int k0 = tk * 32, n0 = tn * 32;
  const int tx = threadIdx.x & 31, ty = threadIdx.x >> 5;
  if (n0 + tx < Nc)
#pragma unroll
    for (int j = 0; j < 4; ++j)
      tile[ty * 4 + j][tx] = src[(long)(k0 + ty * 4 + j) * Nc + n0 + tx];
  __syncthreads();
#pragma unroll
  for (int j = 0; j < 4; ++j) {
    int n = n0 + ty * 4 + j;
    if (n < Nc) dst[(long)n * K + k0 + tx] = f2bf(tile[tx][ty * 4 + j]);
  }
}

__global__ void relu_cvt_x(const float4* __restrict__ x,
                           ushort4* __restrict__ xb) {
  int i = blockIdx.x * blockDim.x + threadIdx.x;
  float4 v = x[i];
  ushort4 o;
  o.x = f2bf(fmaxf(v.x, 0.f));
  o.y = f2bf(fmaxf(v.y, 0.f));
  o.z = f2bf(fmaxf(v.z, 0.f));
  o.w = f2bf(fmaxf(v.w, 0.f));
  xb[i] = o;
}

// 2-phase GEMM, BM=256 x BN=128, BK=32, 8 waves (2M x 4N), dbuf LDS 48 KB.
// T3-minimal schedule (m248): STAGE(t+1); ds_read(t); MFMA; vmcnt(0); barrier.
// Stage-permute swizzle: chunk slot s of row r holds k-chunk (s ^ ((r>>1)&3));
// global source stays 64B-contiguous per row; reads are 2-way (free).
// Optional fused head (w2 != null): per-block 128-col partial dot -> PB.
__global__ __launch_bounds__(512) void gemm2ph(
    const unsigned short* __restrict__ A,
    const unsigned short* __restrict__ Bt,
    const float* __restrict__ bias,
    float* __restrict__ outF,
    unsigned short* __restrict__ outA,
    int K, int Nc,
    const unsigned short* __restrict__ w2,
    float* __restrict__ PB, int r0) {
  __shared__ unsigned short lds[2][1536 * 8];   // 48 KB: A 1024 + B 512 chunks
  __shared__ float part[4][256];                // head partials
  const int tid = threadIdx.x, wave = tid >> 6, lane = tid & 63;
  const int wm = wave >> 2, wn = wave & 3;
  const int lr = lane & 15, lh = lane >> 4;
  const long brow = (long)blockIdx.x * 256;
  const int bcol = blockIdx.y * 128;
  const int nk = K >> 5;
  // read-side swizzle constant (elems): slot = lh ^ ((lr>>1)&3)
  const int axr = (lh ^ ((lr >> 1) & 3)) * 8;

  f32x4 acc[8][2];
#pragma unroll
  for (int m = 0; m < 8; ++m)
#pragma unroll
    for (int n = 0; n < 2; ++n) acc[m][n] = (f32x4){0.f, 0.f, 0.f, 0.f};

  auto STAGE = [&](int t) {
    unsigned short* dst = lds[t & 1];
    const int k0 = t << 5;
#pragma unroll
    for (int i = 0; i < 2; ++i) {               // A: 1024 chunks, 2/thread
      const int cb = i * 512 + wave * 64;
      const int c = cb + lane;
      const int r = c >> 2;
      const int kc = (c & 3) ^ ((r >> 1) & 3);
      gload_lds16(A + (brow + r) * (long)K + k0 + kc * 8, &dst[cb * 8]);
    }
    {                                           // B: 512 chunks, 1/thread
      const int cb = wave * 64;
      const int c = cb + lane;
      const int r = c >> 2;
      const int kc = (c & 3) ^ ((r >> 1) & 3);
      gload_lds16(Bt + (long)(bcol + r) * K + k0 + kc * 8,
                  &dst[(1024 + cb) * 8]);
    }
  };

  STAGE(0);
  asm volatile("s_waitcnt vmcnt(0)" ::: "memory");
  __builtin_amdgcn_s_barrier();
  __builtin_amdgcn_sched_barrier(0);

  for (int t = 0; t < nk; ++t) {
    if (t + 1 < nk) STAGE(t + 1);
    const unsigned short* buf = lds[t & 1];
    bf16x8 a[8], b[2];
#pragma unroll
    for (int m = 0; m < 8; ++m)
      a[m] = *(const bf16x8*)&buf[(wm * 128 + m * 16 + lr) * 32 + axr];
#pragma unroll
    for (int n = 0; n < 2; ++n)
      b[n] = *(const bf16x8*)&buf[1024 * 8 + (wn * 32 + n * 16 + lr) * 32 + axr];
#pragma unroll
    for (int m = 0; m < 8; ++m)
#pragma unroll
      for (int n = 0; n < 2; ++n)
        acc[m][n] =
            __builtin_amdgcn_mfma_f32_16x16x32_bf16(a[m], b[n], acc[m][n], 0, 0, 0);
    asm volatile("s_waitcnt vmcnt(0)" ::: "memory");
    __builtin_amdgcn_s_barrier();
    __builtin_amdgcn_sched_barrier(0);
  }

  float bv[2];
#pragma unroll
  for (int n = 0; n < 2; ++n) bv[n] = bias[bcol + wn * 32 + n * 16 + lr];

  if (!w2) {
#pragma unroll
    for (int m = 0; m < 8; ++m) {
#pragma unroll
      for (int r = 0; r < 4; ++r) {
        long e = brow + wm * 128 + m * 16 + lh * 4 + r;
#pragma unroll
        for (int n = 0; n < 2; ++n) {
          int oc = bcol + wn * 32 + n * 16 + lr;
          float v = acc[m][n][r] + bv[n];
          if (outF) outF[e * Nc + oc] = v;
          if (outA) outA[e * Nc + oc] = f2bf(fmaxf(v, 0.f));
        }
      }
    }
  } else {
    // fused head partial: s[row] = sum over this block's 128 cols of
    // relu(h1 + b) * w2
    float w2v[2];
#pragma unroll
    for (int n = 0; n < 2; ++n) w2v[n] = bf2f(w2[bcol + wn * 32 + n * 16 + lr]);
#pragma unroll
    for (int m = 0; m < 8; ++m) {
#pragma unroll
      for (int r = 0; r < 4; ++r) {
        float s = 0.f;
#pragma unroll
        for (int n = 0; n < 2; ++n)
          s += fmaxf(acc[m][n][r] + bv[n], 0.f) * w2v[n];
#pragma unroll
        for (int off = 1; off < 16; off <<= 1) s += __shfl_xor(s, off);
        if (lr == 0) part[wn][wm * 128 + m * 16 + lh * 4 + r] = s;
      }
    }
    __syncthreads();
    if (tid < 256)
      PB[(long)blockIdx.y * NE + r0 + brow + tid] =
          part[0][tid] + part[1][tid] + part[2][tid] + part[3][tid];
  }
}

__global__ void head_final(const float* __restrict__ PB,
                           const float* __restrict__ Sb2,
                           const int* __restrict__ y,
                           const int* __restrict__ pairs,
                           float* __restrict__ outR, float* __restrict__ outS,
                           float* __restrict__ outM) {
  const int n = blockIdx.x * 256 + threadIdx.x;
  const int p = blockIdx.y;
  float logit = PB[(long)p * 2 * NE + n] + PB[(long)(p * 2 + 1) * NE + n] +
                Sb2[p];
  float s = 1.f / (1.f + expf(-logit));
  s = fmaxf(s, 1e-9f);
  float r = (1.f - s) / s;
  int yv = y[n];
  float mf = (yv == pairs[p * 2] || yv == pairs[p * 2 + 1]) ? 1.f : 0.f;
  outR[(long)p * NE + n] = r * mf;
  outS[(long)p * NE + n] = s * mf;
  outM[(long)p * NE + n] = mf;
}

extern "C" void kernel_launch(void* const* d_in, const int* in_sizes, int n_in,
                              void* d_out, int out_size, void* d_ws, size_t ws_size,
                              hipStream_t stream) {
  const float* x   = (const float*)d_in[0];
  const int*   y   = (const int*)d_in[1];
  const int*   prs = (const int*)d_in[2];
  const float* W0  = (const float*)d_in[3];
  const float* b0  = (const float*)d_in[4];
  const float* W1  = (const float*)d_in[5];
  const float* b1  = (const float*)d_in[6];
  const float* W2  = (const float*)d_in[7];
  const float* b2  = (const float*)d_in[8];
  const float* SW0 = (const float*)d_in[9];
  const float* Sb0 = (const float*)d_in[10];
  const float* SW1 = (const float*)d_in[11];
  const float* Sb1 = (const float*)d_in[12];
  const float* SW2 = (const float*)d_in[13];
  const float* Sb2 = (const float*)d_in[14];

  uint8_t* ws = (uint8_t*)d_ws;
  size_t off = 0;
  auto take = [&](size_t bytes) -> void* {
    void* ptr = ws + off;
    off = (off + bytes + 255) & ~(size_t)255;
    return ptr;
  };
  unsigned short* W0t  = (unsigned short*)take((size_t)64 * 512 * 2);
  unsigned short* W1t  = (unsigned short*)take((size_t)512 * 512 * 2);
  unsigned short* W2t  = (unsigned short*)take((size_t)512 * 512 * 2);
  unsigned short* SW0t = (unsigned short*)take((size_t)3 * 512 * 512 * 2);
  unsigned short* SW1t = (unsigned short*)take((size_t)3 * 256 * 512 * 2);
  unsigned short* SW2b = (unsigned short*)take((size_t)3 * 256 * 2);
  unsigned short* Xb   = (unsigned short*)take((size_t)NE * 64 * 2);
  float*          PB   = (float*)take((size_t)6 * NE * 4);
  const size_t fixed = off;

  // pick largest row-chunk whose 3 activation buffers fit the workspace
  long chunk = NE;
  while (chunk > 16384 && fixed + (size_t)3 * chunk * 1024 + 4096 > ws_size)
    chunk >>= 1;

  unsigned short* T0   = (unsigned short*)take((size_t)chunk * 512 * 2);
  unsigned short* T1   = (unsigned short*)take((size_t)chunk * 512 * 2);
  unsigned short* bufR = (unsigned short*)take((size_t)chunk * 512 * 2);
  unsigned short* H    = T0;   // alias: T0 dead after L1 consumes it

  float* out   = (float*)d_out;
  float* outRe = out;
  float* outR  = out + (size_t)NE * 512;
  float* outS  = outR + (size_t)3 * NE;
  float* outM  = outS + (size_t)3 * NE;

  weight_prep<<<dim3(256, 12), 256, 0, stream>>>(W0, W1, W2, SW0, SW1, SW2,
                                                 W0t, W1t, W2t, SW0t, SW1t, SW2b);
  relu_cvt_x<<<dim3(NE * 64 / 4 / 256), 256, 0, stream>>>((const float4*)x,
                                                          (ushort4*)Xb);

  for (long r0 = 0; r0 < NE; r0 += chunk) {
    // trunk: Xb -> T0 -> T1 -> (repr fp32, bufR bf16)
    gemm2ph<<<dim3(chunk / 256, 4), 512, 0, stream>>>(
        Xb + r0 * 64, W0t, b0, nullptr, T0, 64, 512, nullptr, nullptr, 0);
    gemm2ph<<<dim3(chunk / 256, 4), 512, 0, stream>>>(
        T0, W1t, b1, nullptr, T1, 512, 512, nullptr, nullptr, 0);
    gemm2ph<<<dim3(chunk / 256, 4), 512, 0, stream>>>(
        T1, W2t, b2, outRe + r0 * 512, bufR, 512, 512, nullptr, nullptr, 0);
    // per-pair subnets: SW0 -> H (L3-hot), SW1 + head partials
    for (int p = 0; p < 3; ++p) {
      gemm2ph<<<dim3(chunk / 256, 4), 512, 0, stream>>>(
          bufR, SW0t + (size_t)p * 512 * 512, Sb0 + (size_t)p * 512, nullptr,
          H, 512, 512, nullptr, nullptr, 0);
      gemm2ph<<<dim3(chunk / 256, 2), 512, 0, stream>>>(
          H, SW1t + (size_t)p * 256 * 512, Sb1 + (size_t)p * 256, nullptr,
          nullptr, 512, 256, SW2b + (size_t)p * 256, PB + (size_t)p * 2 * NE,
          (int)r0);
    }
  }
  head_final<<<dim3(NE / 256, 3), 256, 0, stream>>>(PB, Sb2, y, prs,
                                                    outR, outS, outM);
}

// Round 7
// 735.797 us; speedup vs baseline: 1.6361x; 1.1990x over previous
//
#include <hip/hip_runtime.h>
#include <stdint.h>

#define NE 131072

typedef __attribute__((ext_vector_type(8))) short bf16x8;
typedef __attribute__((ext_vector_type(4))) float f32x4;

static __device__ __forceinline__ unsigned short f2bf(float f) {
  unsigned u = __float_as_uint(f);
  u += 0x7FFF + ((u >> 16) & 1);   // round-to-nearest-even
  return (unsigned short)(u >> 16);
}
static __device__ __forceinline__ float bf2f(unsigned short h) {
  return __uint_as_float((unsigned)h << 16);
}
static __device__ __forceinline__ void gload_lds16(const void* g, void* l) {
  __builtin_amdgcn_global_load_lds(
      (const __attribute__((address_space(1))) unsigned*)g,
      (__attribute__((address_space(3))) unsigned*)l, 16, 0, 0);
}

// Fused weight prep (verified R4-R6): dst[n][k] = bf16(src[k][n])
__global__ void weight_prep(const float* __restrict__ W0, const float* __restrict__ W1,
                            const float* __restrict__ W2, const float* __restrict__ SW0,
                            const float* __restrict__ SW1, const float* __restrict__ SW2,
                            unsigned short* W0t, unsigned short* W1t,
                            unsigned short* W2t, unsigned short* SW0t,
                            unsigned short* SW1t, unsigned short* SW2b) {
  __shared__ float tile[32][33];
  const int u = blockIdx.y;
  const float* src; unsigned short* dst; int K, Nc;
  if (u == 0)      { src = W0;  dst = W0t;  K = 64;  Nc = 512; }
  else if (u == 1) { src = W1;  dst = W1t;  K = 512; Nc = 512; }
  else if (u == 2) { src = W2;  dst = W2t;  K = 512; Nc = 512; }
  else if (u < 6)  { int p = u - 3; src = SW0 + (long)p * 512 * 512; dst = SW0t + (long)p * 512 * 512; K = 512; Nc = 512; }
  else if (u < 9)  { int p = u - 6; src = SW1 + (long)p * 512 * 256; dst = SW1t + (long)p * 256 * 512; K = 512; Nc = 256; }
  else             { int p = u - 9; src = SW2 + (long)p * 256;       dst = SW2b + (long)p * 256;       K = 256; Nc = 1; }
  const int tkn = K >> 5;
  const int tk = blockIdx.x % tkn, tn = blockIdx.x / tkn;
  if (tn >= ((Nc + 31) >> 5)) return;
  const int k0 = tk * 32, n0 = tn * 32;
  const int tx = threadIdx.x & 31, ty = threadIdx.x >> 5;
  if (n0 + tx < Nc)
#pragma unroll
    for (int j = 0; j < 4; ++j)
      tile[ty * 4 + j][tx] = src[(long)(k0 + ty * 4 + j) * Nc + n0 + tx];
  __syncthreads();
#pragma unroll
  for (int j = 0; j < 4; ++j) {
    int n = n0 + ty * 4 + j;
    if (n < Nc) dst[(long)n * K + k0 + tx] = f2bf(tile[tx][ty * 4 + j]);
  }
}

__global__ void relu_cvt_x(const float4* __restrict__ x,
                           ushort4* __restrict__ xb) {
  int i = blockIdx.x * blockDim.x + threadIdx.x;
  float4 v = x[i];
  ushort4 o;
  o.x = f2bf(fmaxf(v.x, 0.f));
  o.y = f2bf(fmaxf(v.y, 0.f));
  o.z = f2bf(fmaxf(v.z, 0.f));
  o.w = f2bf(fmaxf(v.w, 0.f));
  xb[i] = o;
}

// 2-phase GEMM, BM=256 x BN=128, BK=32, 8 waves (2M x 4N), dbuf LDS 48 KB.
// T3-minimal schedule: STAGE(t+1); ds_read(t); MFMA; vmcnt(0); barrier.
// Stage-permute swizzle (conflict-free reads, coalesced source) verified R6.
// Grouped over blockIdx.z via element strides. Optional fused head partial.
__global__ __launch_bounds__(512) void gemm2ph(
    const unsigned short* __restrict__ A, long aZ,
    const unsigned short* __restrict__ Bt, long bZ,
    const float* __restrict__ bias, long biasZ,
    float* __restrict__ outF,
    unsigned short* __restrict__ outA, long cZ,
    int K, int Nc,
    const unsigned short* __restrict__ w2, long w2Z,
    float* __restrict__ PB, long pbZ, int r0) {
  __shared__ unsigned short lds[2][1536 * 8];   // 48 KB: A 1024 + B 512 chunks
  __shared__ float part[4][256];                // head partials
  const int z = blockIdx.z;
  A += (long)z * aZ;
  Bt += (long)z * bZ;
  bias += (long)z * biasZ;
  if (outA) outA += (long)z * cZ;
  if (w2) { w2 += (long)z * w2Z; PB += (long)z * pbZ; }

  const int tid = threadIdx.x, wave = tid >> 6, lane = tid & 63;
  const int wm = wave >> 2, wn = wave & 3;
  const int lr = lane & 15, lh = lane >> 4;
  const long brow = (long)blockIdx.x * 256;
  const int bcol = blockIdx.y * 128;
  const int nk = K >> 5;
  // read-side swizzle constant (elems): slot = lh ^ ((lr>>1)&3)
  const int axr = (lh ^ ((lr >> 1) & 3)) * 8;

  f32x4 acc[8][2];
#pragma unroll
  for (int m = 0; m < 8; ++m)
#pragma unroll
    for (int n = 0; n < 2; ++n) acc[m][n] = (f32x4){0.f, 0.f, 0.f, 0.f};

  auto STAGE = [&](int t) {
    unsigned short* dst = lds[t & 1];
    const int k0 = t << 5;
#pragma unroll
    for (int i = 0; i < 2; ++i) {               // A: 1024 chunks, 2/thread
      const int cb = i * 512 + wave * 64;
      const int c = cb + lane;
      const int r = c >> 2;
      const int kc = (c & 3) ^ ((r >> 1) & 3);
      gload_lds16(A + (brow + r) * (long)K + k0 + kc * 8, &dst[cb * 8]);
    }
    {                                           // B: 512 chunks, 1/thread
      const int cb = wave * 64;
      const int c = cb + lane;
      const int r = c >> 2;
      const int kc = (c & 3) ^ ((r >> 1) & 3);
      gload_lds16(Bt + (long)(bcol + r) * K + k0 + kc * 8,
                  &dst[(1024 + cb) * 8]);
    }
  };

  STAGE(0);
  asm volatile("s_waitcnt vmcnt(0)" ::: "memory");
  __builtin_amdgcn_s_barrier();
  __builtin_amdgcn_sched_barrier(0);

  for (int t = 0; t < nk; ++t) {
    if (t + 1 < nk) STAGE(t + 1);
    const unsigned short* buf = lds[t & 1];
    bf16x8 a[8], b[2];
#pragma unroll
    for (int m = 0; m < 8; ++m)
      a[m] = *(const bf16x8*)&buf[(wm * 128 + m * 16 + lr) * 32 + axr];
#pragma unroll
    for (int n = 0; n < 2; ++n)
      b[n] = *(const bf16x8*)&buf[1024 * 8 + (wn * 32 + n * 16 + lr) * 32 + axr];
#pragma unroll
    for (int m = 0; m < 8; ++m)
#pragma unroll
      for (int n = 0; n < 2; ++n)
        acc[m][n] =
            __builtin_amdgcn_mfma_f32_16x16x32_bf16(a[m], b[n], acc[m][n], 0, 0, 0);
    asm volatile("s_waitcnt vmcnt(0)" ::: "memory");
    __builtin_amdgcn_s_barrier();
    __builtin_amdgcn_sched_barrier(0);
  }

  float bv[2];
#pragma unroll
  for (int n = 0; n < 2; ++n) bv[n] = bias[bcol + wn * 32 + n * 16 + lr];

  if (!w2) {
#pragma unroll
    for (int m = 0; m < 8; ++m) {
#pragma unroll
      for (int r = 0; r < 4; ++r) {
        long e = brow + wm * 128 + m * 16 + lh * 4 + r;
#pragma unroll
        for (int n = 0; n < 2; ++n) {
          int oc = bcol + wn * 32 + n * 16 + lr;
          float v = acc[m][n][r] + bv[n];
          if (outF) outF[e * Nc + oc] = v;
          if (outA) outA[e * Nc + oc] = f2bf(fmaxf(v, 0.f));
        }
      }
    }
  } else {
    // fused head partial over this block's 128 cols: relu(h1+b) . w2
    float w2v[2];
#pragma unroll
    for (int n = 0; n < 2; ++n) w2v[n] = bf2f(w2[bcol + wn * 32 + n * 16 + lr]);
#pragma unroll
    for (int m = 0; m < 8; ++m) {
#pragma unroll
      for (int r = 0; r < 4; ++r) {
        float s = 0.f;
#pragma unroll
        for (int n = 0; n < 2; ++n)
          s += fmaxf(acc[m][n][r] + bv[n], 0.f) * w2v[n];
#pragma unroll
        for (int off = 1; off < 16; off <<= 1) s += __shfl_xor(s, off);
        if (lr == 0) part[wn][wm * 128 + m * 16 + lh * 4 + r] = s;
      }
    }
    __syncthreads();
    if (tid < 256)
      PB[(long)blockIdx.y * NE + r0 + brow + tid] =
          part[0][tid] + part[1][tid] + part[2][tid] + part[3][tid];
  }
}

__global__ void head_final(const float* __restrict__ PB,
                           const float* __restrict__ Sb2,
                           const int* __restrict__ y,
                           const int* __restrict__ pairs,
                           float* __restrict__ outR, float* __restrict__ outS,
                           float* __restrict__ outM) {
  const int n = blockIdx.x * 256 + threadIdx.x;
  const int p = blockIdx.y;
  float logit = PB[(long)p * 2 * NE + n] + PB[(long)(p * 2 + 1) * NE + n] +
                Sb2[p];
  float s = 1.f / (1.f + expf(-logit));
  s = fmaxf(s, 1e-9f);
  float r = (1.f - s) / s;
  int yv = y[n];
  float mf = (yv == pairs[p * 2] || yv == pairs[p * 2 + 1]) ? 1.f : 0.f;
  outR[(long)p * NE + n] = r * mf;
  outS[(long)p * NE + n] = s * mf;
  outM[(long)p * NE + n] = mf;
}

extern "C" void kernel_launch(void* const* d_in, const int* in_sizes, int n_in,
                              void* d_out, int out_size, void* d_ws, size_t ws_size,
                              hipStream_t stream) {
  const float* x   = (const float*)d_in[0];
  const int*   y   = (const int*)d_in[1];
  const int*   prs = (const int*)d_in[2];
  const float* W0  = (const float*)d_in[3];
  const float* b0  = (const float*)d_in[4];
  const float* W1  = (const float*)d_in[5];
  const float* b1  = (const float*)d_in[6];
  const float* W2  = (const float*)d_in[7];
  const float* b2  = (const float*)d_in[8];
  const float* SW0 = (const float*)d_in[9];
  const float* Sb0 = (const float*)d_in[10];
  const float* SW1 = (const float*)d_in[11];
  const float* Sb1 = (const float*)d_in[12];
  const float* SW2 = (const float*)d_in[13];
  const float* Sb2 = (const float*)d_in[14];

  uint8_t* ws = (uint8_t*)d_ws;
  size_t off = 0;
  auto take = [&](size_t bytes) -> void* {
    void* ptr = ws + off;
    off = (off + bytes + 255) & ~(size_t)255;
    return ptr;
  };
  unsigned short* W0t  = (unsigned short*)take((size_t)64 * 512 * 2);
  unsigned short* W1t  = (unsigned short*)take((size_t)512 * 512 * 2);
  unsigned short* W2t  = (unsigned short*)take((size_t)512 * 512 * 2);
  unsigned short* SW0t = (unsigned short*)take((size_t)3 * 512 * 512 * 2);
  unsigned short* SW1t = (unsigned short*)take((size_t)3 * 256 * 512 * 2);
  unsigned short* SW2b = (unsigned short*)take((size_t)3 * 256 * 2);
  unsigned short* Xb   = (unsigned short*)take((size_t)NE * 64 * 2);
  float*          PB   = (float*)take((size_t)6 * NE * 4);
  const size_t fixed = off;

  // Chunk CAPPED at 32768 rows so the producer->consumer working set
  // (T0+T1 or bufR+H3) stays well inside the 256 MB L3 (R6 lesson:
  // chunk=NE pushed 134MB buffers -> L3 thrash -> 700MB HBM/dispatch).
  long chunk = 32768;
  while (chunk > 8192 && fixed + (size_t)6 * chunk * 1024 + 4096 > ws_size)
    chunk >>= 1;

  unsigned short* T0   = (unsigned short*)take((size_t)chunk * 512 * 2);
  unsigned short* T1   = (unsigned short*)take((size_t)chunk * 512 * 2);
  unsigned short* bufR = (unsigned short*)take((size_t)chunk * 512 * 2);
  unsigned short* H3   = (unsigned short*)take((size_t)3 * chunk * 512 * 2);

  float* out   = (float*)d_out;
  float* outRe = out;
  float* outR  = out + (size_t)NE * 512;
  float* outS  = outR + (size_t)3 * NE;
  float* outM  = outS + (size_t)3 * NE;

  weight_prep<<<dim3(256, 12), 256, 0, stream>>>(W0, W1, W2, SW0, SW1, SW2,
                                                 W0t, W1t, W2t, SW0t, SW1t, SW2b);
  relu_cvt_x<<<dim3(NE * 64 / 4 / 256), 256, 0, stream>>>((const float4*)x,
                                                          (ushort4*)Xb);

  for (long r0 = 0; r0 < NE; r0 += chunk) {
    // trunk: Xb -> T0 -> T1 -> (repr fp32, bufR bf16)
    gemm2ph<<<dim3(chunk / 256, 4, 1), 512, 0, stream>>>(
        Xb + r0 * 64, 0, W0t, 0, b0, 0, nullptr, T0, 0, 64, 512,
        nullptr, 0, nullptr, 0, 0);
    gemm2ph<<<dim3(chunk / 256, 4, 1), 512, 0, stream>>>(
        T0, 0, W1t, 0, b1, 0, nullptr, T1, 0, 512, 512,
        nullptr, 0, nullptr, 0, 0);
    gemm2ph<<<dim3(chunk / 256, 4, 1), 512, 0, stream>>>(
        T1, 0, W2t, 0, b2, 0, outRe + r0 * 512, bufR, 0, 512, 512,
        nullptr, 0, nullptr, 0, 0);
    // SW0 batched over p: bufR -> H3[p]
    gemm2ph<<<dim3(chunk / 256, 4, 3), 512, 0, stream>>>(
        bufR, 0, SW0t, (long)512 * 512, Sb0, 512, nullptr,
        H3, (long)chunk * 512, 512, 512,
        nullptr, 0, nullptr, 0, 0);
    // SW1 + head partials, batched over p
    gemm2ph<<<dim3(chunk / 256, 2, 3), 512, 0, stream>>>(
        H3, (long)chunk * 512, SW1t, (long)256 * 512, Sb1, 256, nullptr,
        nullptr, 0, 512, 256,
        SW2b, 256, PB, (long)2 * NE, (int)r0);
  }
  head_final<<<dim3(NE / 256, 3), 256, 0, stream>>>(PB, Sb2, y, prs,
                                                    outR, outS, outM);
}